// Round 4
// baseline (128.021 us; speedup 1.0000x reference)
//
#include <hip/hip_runtime.h>

#define NRAYS 4096
#define NSTEPS 160
#define NSAMP (NRAYS*NSTEPS)
#define GG 160
#define GG2 (GG*GG)
#define GG3 (GG*GG2)
#define GM 80
#define GM2 (GM*GM)

#define NEARV 0.05f
#define DISTV 0.00625f
#define SVAL 80.0f
#define ACT_SHIFT_C (-9.2102403669758813f)
#define INV2H 40.0f          // 1/(2*VOXEL_SIZE)
#define MASK_THRES_C 1e-3f
#define FAST_THRES_C 1e-7f

// normalized 5-tap gaussian, sigma=1
#define KW0 0.05448868454964295f
#define KW1 0.24420134200323332f
#define KW2 0.40261994689424750f

__device__ __forceinline__ float sigmf(float x){ return 1.0f/(1.0f+__expf(-x)); }
__device__ __forceinline__ float softplusf_(float x){ return (x>20.0f)? x : log1pf(__expf(x)); }

__device__ __forceinline__ void tricoord(float p, int Gx, int& i0, float& fr){
  float u = (p + 1.0f)*0.5f*(float)(Gx-1);
  u = fminf(fmaxf(u, 0.0f), (float)(Gx-1));
  int i = (int)floorf(u);
  i = min(max(i,0), Gx-2);
  i0 = i; fr = u - (float)i;
}

// ---------------- fused y+z gaussian passes (zero-pad SAME), LDS tiled ----------------
// block 0 additionally zero-inits out[0..3N) and cnt (stream-ordered before consumers).
__global__ __launch_bounds__(256) void ksmooth_yz(const float* __restrict__ in, float* __restrict__ out,
                                                  float* __restrict__ outbuf, int* __restrict__ cnt){
  __shared__ float S[36][37];
  __shared__ float Tz[36][33];
  const int bx = blockIdx.x;          // 160 * 25
  const int t = threadIdx.x;
  if (bx == 0){
    for (int i = t; i < NRAYS*3; i += 256) outbuf[i] = 0.0f;
    if (t == 0) *cnt = 0;
  }
  const int x  = bx / 25;
  const int tile = bx % 25;
  const int Y0 = (tile/5)*32, Z0 = (tile%5)*32;
  const float kw[5] = {KW0,KW1,KW2,KW1,KW0};
  for (int i = t; i < 36*36; i += 256){
    int r = i/36, c = i - (i/36)*36;
    int y = Y0 + r - 2, z = Z0 + c - 2;
    float v = 0.0f;
    if (y>=0 && y<GG && z>=0 && z<GG) v = in[(x*GG+y)*GG+z];
    S[r][c] = v;
  }
  __syncthreads();
  for (int i = t; i < 36*32; i += 256){
    int r = i >> 5, c = i & 31;
    float acc = 0.f;
    #pragma unroll
    for (int d=0; d<5; d++) acc += kw[d]*S[r][c+d];
    Tz[r][c] = acc;
  }
  __syncthreads();
  for (int i = t; i < 32*32; i += 256){
    int yy = i >> 5, c = i & 31;
    float acc = 0.f;
    #pragma unroll
    for (int d=0; d<5; d++) acc += kw[d]*Tz[yy+d][c];
    out[(x*GG + Y0+yy)*GG + Z0 + c] = acc;
  }
}

// ---------------- x-axis gaussian pass: sliding register window ----------------
#define XCH 32
__global__ __launch_bounds__(256) void ksmooth_x(const float* __restrict__ in, float* __restrict__ out){
  const int bid = blockIdx.x;             // (GG2/256) * (GG/XCH) = 100*5 = 500
  const int xc  = bid / (GG2/256);
  const int o   = (bid % (GG2/256))*256 + threadIdx.x;   // y*GG+z, coalesced
  const int x0  = xc*XCH;
  float w0 = (x0 >= 2) ? in[(x0-2)*GG2 + o] : 0.0f;
  float w1 = (x0 >= 1) ? in[(x0-1)*GG2 + o] : 0.0f;
  float w2 = in[x0*GG2 + o];
  float w3 = in[(x0+1)*GG2 + o];
  #pragma unroll 8
  for (int i = 0; i < XCH; i++){
    int xx = x0 + i;
    float w4 = (xx+2 < GG) ? in[(xx+2)*GG2 + o] : 0.0f;
    out[xx*GG2 + o] = KW0*w0 + KW1*w1 + KW2*w2 + KW1*w3 + KW0*w4;
    w0=w1; w1=w2; w2=w3; w3=w4;
  }
}

// ---------------- wave-parallel march: 1 ray = 1 wave, 64-step speculative chunks ----------------
// Exactness: keep1 test uses the exact per-step T1 (from product-scan); once T1 <= 1e-7 at the
// chunk end, all later steps fail the strict > 1e-7 test, so stopping is exact for any data.
__global__ __launch_bounds__(256) void kmarch(
  const float* __restrict__ ro, const float* __restrict__ rd,
  const float* __restrict__ vd, const float* __restrict__ maskg,
  const float* __restrict__ sdfs,
  int* __restrict__ slist, float* __restrict__ sw, float* __restrict__ sgrad,
  int* __restrict__ cnt, float* __restrict__ out)
{
  const int wid  = (blockIdx.x*256 + threadIdx.x) >> 6;   // ray id
  const int lane = threadIdx.x & 63;
  if (wid >= NRAYS) return;
  const int n = wid;
  const float ox=ro[n*3+0], oy=ro[n*3+1], oz=ro[n*3+2];
  const float dx=rd[n*3+0], dy=rd[n*3+1], dz=rd[n*3+2];
  const float vx=vd[n*3+0], vy=vd[n*3+1], vz=vd[n*3+2];
  float T1c=1.0f, T2c=1.0f, cum=0.0f;

  for (int ch = 0; ch < (NSTEPS+63)/64; ch++){
    const int s = ch*64 + lane;
    float alpha = 0.0f, gx=0.0f, gy=0.0f, gz=0.0f;
    {
      const float tt = NEARV + DISTV*(float)(s < NSTEPS ? s : NSTEPS-1);
      const float px = ox + dx*tt, py = oy + dy*tt, pz = oz + dz*tt;

      int mx,my,mz; float mfx,mfy,mfz;
      tricoord(px, GM, mx, mfx); tricoord(py, GM, my, mfy); tricoord(pz, GM, mz, mfz);
      int mid = (mx*GM + my)*GM + mz;
      float d000=maskg[mid],        d001=maskg[mid+1];
      float d010=maskg[mid+GM],     d011=maskg[mid+GM+1];
      float d100=maskg[mid+GM2],    d101=maskg[mid+GM2+1];
      float d110=maskg[mid+GM2+GM], d111=maskg[mid+GM2+GM+1];
      float m00 = d000 + (d001-d000)*mfz;
      float m01 = d010 + (d011-d010)*mfz;
      float m10 = d100 + (d101-d100)*mfz;
      float m11 = d110 + (d111-d110)*mfz;
      float m0 = m00 + (m01-m00)*mfy;
      float m1 = m10 + (m11-m10)*mfy;
      float dens = m0 + (m1-m0)*mfx;
      float malpha = 1.0f - __expf(-softplusf_(dens + ACT_SHIFT_C)*DISTV);

      int ix,iy,iz; float fx,fy,fz;
      tricoord(px, GG, ix, fx); tricoord(py, GG, iy, fy); tricoord(pz, GG, iz, fz);
      float sdf=0.0f;
      #pragma unroll
      for (int ca=0; ca<2; ca++){
        #pragma unroll
        for (int cb=0; cb<2; cb++){
          #pragma unroll
          for (int cc=0; cc<2; cc++){
            int a=ix+ca, b=iy+cb, c=iz+cc;
            float w = (ca?fx:1.0f-fx)*(cb?fy:1.0f-fy)*(cc?fz:1.0f-fz);
            int id = (a*GG + b)*GG + c;
            sdf += w*sdfs[id];
            if (a>=1 && a<=GG-2) gx += w*INV2H*(sdfs[id+GG2]-sdfs[id-GG2]);
            if (b>=1 && b<=GG-2) gy += w*INV2H*(sdfs[id+GG]-sdfs[id-GG]);
            if (c>=1 && c<=GG-2) gz += w*INV2H*(sdfs[id+1]-sdfs[id-1]);
          }
        }
      }
      float tc = vx*gx + vy*gy + vz*gz;
      float icos = fminf(tc, 0.0f);
      float e = icos*DISTV*0.5f;
      float prev = sigmf((sdf - e)*SVAL);
      float nxt  = sigmf((sdf + e)*SVAL);
      float a_ = (prev - nxt + 1e-5f)/(prev + 1e-5f);
      a_ = fminf(fmaxf(a_, 0.0f), 1.0f);
      if (!(malpha >= MASK_THRES_C)) a_ = 0.0f;
      alpha = (s < NSTEPS) ? a_ : 0.0f;
    }

    // ---- scan 1: exclusive product of (1-alpha) ----
    float p = 1.0f - alpha;
    #pragma unroll
    for (int d=1; d<64; d<<=1){ float q = __shfl_up(p, d, 64); if (lane >= d) p *= q; }
    float excl1 = __shfl_up(p, 1, 64); if (lane == 0) excl1 = 1.0f;
    float w1 = alpha * (T1c * excl1);
    float a2 = (w1 > FAST_THRES_C) ? alpha : 0.0f;

    // ---- scan 2: exclusive product of (1-alpha2) ----
    float p2 = 1.0f - a2;
    #pragma unroll
    for (int d=1; d<64; d<<=1){ float q = __shfl_up(p2, d, 64); if (lane >= d) p2 *= q; }
    float excl2 = __shfl_up(p2, 1, 64); if (lane == 0) excl2 = 1.0f;
    float wv = a2 * (T2c * excl2);
    cum += wv;

    // ---- compaction (order-independent downstream) ----
    unsigned long long m = __ballot(wv > 0.0f);
    if (m){
      int tot = __popcll(m);
      int leader = __builtin_ctzll(m);
      int basep = 0;
      if (lane == leader) basep = atomicAdd(cnt, tot);
      basep = __shfl(basep, leader, 64);
      if (wv > 0.0f){
        int pos = basep + __popcll(m & ((1ull<<lane)-1ull));
        slist[pos] = n*NSTEPS + s;
        sw[pos] = wv;
        sgrad[pos*3+0]=gx; sgrad[pos*3+1]=gy; sgrad[pos*3+2]=gz;
      }
    }

    T1c *= __shfl(p, 63, 64);
    T2c *= __shfl(p2, 63, 64);
    if (T1c <= FAST_THRES_C) break;
  }

  #pragma unroll
  for (int d=1; d<64; d<<=1) cum += __shfl_xor(cum, d, 64);
  if (lane == 0){
    out[NRAYS*3 + n] = T2c;
    out[NRAYS*4 + n] = 1.0f - cum;
  }
}

// ---------------- compacted MLP: one head per block, 8 samples, 32 thr/sample ----------------
__global__ __launch_bounds__(256) void kmlp3(
  const float* __restrict__ ro, const float* __restrict__ rd,
  const float* __restrict__ vd, const int* __restrict__ em,
  const float* __restrict__ offc, const float* __restrict__ emoc,
  const int* __restrict__ slist, const float* __restrict__ sw,
  const float* __restrict__ sgrad, const int* __restrict__ cnt,
  const float* __restrict__ W0o, const float* __restrict__ b0o,
  const float* __restrict__ W1o, const float* __restrict__ b1o,
  const float* __restrict__ W2o, const float* __restrict__ b2o,
  const float* __restrict__ W0e, const float* __restrict__ b0e,
  const float* __restrict__ W1e, const float* __restrict__ b1e,
  const float* __restrict__ W2e, const float* __restrict__ b2e,
  float* __restrict__ out)
{
  __shared__ float X[8][80];
  __shared__ float H[8][132];
  __shared__ float H2[8][132];
  __shared__ float OUTB[8][3];
  __shared__ float WSH[8];
  __shared__ float GS[8][3];
  __shared__ int SSAMP[8];
  __shared__ int SEM[8];
  __shared__ int s_go;

  const int t = threadIdx.x;
  const int count = *cnt;
  const int head = blockIdx.x & 1;
  const int cstride = gridDim.x >> 1;

  const float* W0 = head ? W0e : W0o;  const float* b0 = head ? b0e : b0o;
  const float* W1 = head ? W1e : W1o;  const float* b1 = head ? b1e : b1o;
  const float* W2 = head ? W2e : W2o;  const float* b2 = head ? b2e : b2o;
  const float* cg = head ? emoc : offc;
  const float4* W04 = (const float4*)W0;
  const float4* W14 = (const float4*)W1;

  const int sp   = t >> 5;     // sample 0..7
  const int lane = t & 31;     // 32 threads per sample, 4 outputs each

  for (int chunk = blockIdx.x >> 1; chunk*8 < count; chunk += cstride) {
    const int base = chunk*8;
    if (t == 0) s_go = 0;
    if (t < 8) {
      int i = base + t;
      bool vld = (i < count);
      int samp = vld ? slist[i] : 0;
      SSAMP[t] = samp;
      WSH[t]   = vld ? sw[i] : 0.0f;
      GS[t][0] = vld ? sgrad[i*3+0] : 0.0f;
      GS[t][1] = vld ? sgrad[i*3+1] : 0.0f;
      GS[t][2] = vld ? sgrad[i*3+2] : 0.0f;
      SEM[t]   = vld ? em[samp/NSTEPS] : 0;
    }
    __syncthreads();
    if (t < 8) {
      bool live = (WSH[t] > 0.0f) && (head == 0 || SEM[t] != 0);
      if (live) s_go = 1;
    }
    __syncthreads();

    if (s_go) {
      // ---- features: s = t&7 sample, r = t>>3 group (0..31, 10 used) ----
      {
        const int s = t & 7;
        const int r = t >> 3;
        const int samp = SSAMP[s];
        const int n = samp / NSTEPS;
        const int step = samp - n*NSTEPS;
        const float tt = NEARV + DISTV*(float)step;
        const float px = ro[n*3+0] + rd[n*3+0]*tt;
        const float py = ro[n*3+1] + rd[n*3+1]*tt;
        const float pz = ro[n*3+2] + rd[n*3+2]*tt;
        if (r < 3) {
          int ix,iy,iz; float fx,fy,fz;
          tricoord(px, GG, ix, fx); tricoord(py, GG, iy, fy); tricoord(pz, GG, iz, fz);
          const float* g = cg + (size_t)r * GG3;
          const int id = (ix*GG + iy)*GG + iz;
          float v000=g[id],        v001=g[id+1];
          float v010=g[id+GG],     v011=g[id+GG+1];
          float v100=g[id+GG2],    v101=g[id+GG2+1];
          float v110=g[id+GG2+GG], v111=g[id+GG2+GG+1];
          float c00 = v000 + (v001-v000)*fz;
          float c01 = v010 + (v011-v010)*fz;
          float c10 = v100 + (v101-v100)*fz;
          float c11 = v110 + (v111-v110)*fz;
          float c0 = c00 + (c01-c00)*fy;
          float c1 = c10 + (c11-c10)*fy;
          X[s][r] = c0 + (c1-c0)*fx;
        } else if (r == 3) {
          X[s][3] = (px+1.0f)*0.5f;
          X[s][4] = (py+1.0f)*0.5f;
          X[s][5] = (pz+1.0f)*0.5f;
          float gx = GS[s][0], gy = GS[s][1], gz = GS[s][2];
          float inv = 1.0f/(sqrtf(gx*gx+gy*gy+gz*gz)+1e-5f);
          X[s][72] = gx*inv; X[s][73] = gy*inv; X[s][74] = gz*inv;
        } else if (r < 7) {
          const int a = r - 4;
          const float coord = (a==0)?px:((a==1)?py:pz);
          const float rxyz = (coord+1.0f)*0.5f;
          float fr = 1.0f;
          #pragma unroll
          for (int q = 0; q < 5; q++) {
            float e = rxyz*fr; fr *= 2.0f;
            X[s][6  + a*5 + q] = __sinf(e);
            X[s][21 + a*5 + q] = __cosf(e);
          }
        } else if (r < 10) {
          const int a = r - 7;
          const float v = vd[n*3+a];
          float fr = 1.0f;
          #pragma unroll
          for (int q = 0; q < 4; q++) {
            float e = v*fr; fr *= 2.0f;
            X[s][36 + a*4 + q] = e;
            X[s][48 + a*4 + q] = __sinf(e);
            X[s][60 + a*4 + q] = __cosf(e);
          }
        }
      }
      __syncthreads();

      // ---- layer 0: 75 -> 128 ----
      {
        float4 acc = ((const float4*)b0)[lane];
        #pragma unroll 5
        for (int k=0; k<75; k++){
          float x = X[sp][k];
          float4 w = W04[k*32 + lane];
          acc.x += x*w.x; acc.y += x*w.y; acc.z += x*w.z; acc.w += x*w.w;
        }
        H[sp][lane*4+0] = fmaxf(acc.x,0.0f);
        H[sp][lane*4+1] = fmaxf(acc.y,0.0f);
        H[sp][lane*4+2] = fmaxf(acc.z,0.0f);
        H[sp][lane*4+3] = fmaxf(acc.w,0.0f);
      }
      __syncthreads();

      // ---- layer 1: 128 -> 128 ----
      {
        float4 acc = ((const float4*)b1)[lane];
        #pragma unroll 8
        for (int k=0; k<128; k++){
          float x = H[sp][k];
          float4 w = W14[k*32 + lane];
          acc.x += x*w.x; acc.y += x*w.y; acc.z += x*w.z; acc.w += x*w.w;
        }
        H2[sp][lane*4+0] = fmaxf(acc.x,0.0f);
        H2[sp][lane*4+1] = fmaxf(acc.y,0.0f);
        H2[sp][lane*4+2] = fmaxf(acc.z,0.0f);
        H2[sp][lane*4+3] = fmaxf(acc.w,0.0f);
      }
      __syncthreads();

      // ---- layer 2: 128 -> 3, 32-lane shuffle reduce ----
      {
        float a0=0.0f, a1=0.0f, a2v=0.0f;
        #pragma unroll
        for (int i=0;i<4;i++){
          int k = lane*4+i;
          float h = H2[sp][k];
          a0  += h*W2[k*3+0];
          a1  += h*W2[k*3+1];
          a2v += h*W2[k*3+2];
        }
        #pragma unroll
        for (int d=16; d>=1; d>>=1){
          a0  += __shfl_down(a0,  d, 32);
          a1  += __shfl_down(a1,  d, 32);
          a2v += __shfl_down(a2v, d, 32);
        }
        if (lane == 0){
          OUTB[sp][0] = sigmf(a0  + b2[0]);
          OUTB[sp][1] = sigmf(a1  + b2[1]);
          OUTB[sp][2] = sigmf(a2v + b2[2]);
        }
      }
      __syncthreads();

      if (t < 24) {
        int s2 = t/3, c = t - s2*3;
        float w = WSH[s2];
        if (w > 0.0f && (head == 0 || SEM[s2] != 0)) {
          int n2 = SSAMP[s2]/NSTEPS;
          atomicAdd(&out[n2*3 + c], w * OUTB[s2][c]);
        }
      }
    }
    __syncthreads();
  }
}

extern "C" void kernel_launch(void* const* d_in, const int* in_sizes, int n_in,
                              void* d_out, int out_size, void* d_ws, size_t ws_size,
                              hipStream_t stream) {
  const float* ro    = (const float*)d_in[0];
  const float* rd    = (const float*)d_in[1];
  const float* vd    = (const float*)d_in[2];
  const int*   em    = (const int*)d_in[3];
  const float* sdfg  = (const float*)d_in[4];
  const float* maskg = (const float*)d_in[5];
  const float* offc  = (const float*)d_in[6];
  const float* emoc  = (const float*)d_in[7];
  const float* W0o = (const float*)d_in[8];
  const float* b0o = (const float*)d_in[9];
  const float* W1o = (const float*)d_in[10];
  const float* b1o = (const float*)d_in[11];
  const float* W2o = (const float*)d_in[12];
  const float* b2o = (const float*)d_in[13];
  const float* W0e = (const float*)d_in[14];
  const float* b0e = (const float*)d_in[15];
  const float* W1e = (const float*)d_in[16];
  const float* b1e = (const float*)d_in[17];
  const float* W2e = (const float*)d_in[18];
  const float* b2e = (const float*)d_in[19];

  float* out = (float*)d_out;
  float* ws  = (float*)d_ws;
  float* bufA  = ws;                         // GG3
  float* bufB  = ws + GG3;                   // GG3
  float* swb   = ws + 2*GG3;                 // NSAMP
  float* sgradb= swb + NSAMP;                // 3*NSAMP
  int*   slist = (int*)(sgradb + 3*(size_t)NSAMP);  // NSAMP
  int*   cnt   = slist + NSAMP;              // 1

  ksmooth_yz<<<GG*25, 256, 0, stream>>>(sdfg, bufB, out, cnt);
  ksmooth_x<<<(GG2/256)*(GG/XCH), 256, 0, stream>>>(bufB, bufA);

  kmarch<<<NRAYS/4, 256, 0, stream>>>(ro, rd, vd, maskg, bufA,
                                      slist, swb, sgradb, cnt, out);

  kmlp3<<<2048, 256, 0, stream>>>(ro, rd, vd, em, offc, emoc,
                                  slist, swb, sgradb, cnt,
                                  W0o,b0o,W1o,b1o,W2o,b2o,
                                  W0e,b0e,W1e,b1e,W2e,b2e, out);
}

// Round 5
// 75.866 us; speedup vs baseline: 1.6875x; 1.6875x over previous
//
#include <hip/hip_runtime.h>

#define NRAYS 4096
#define NSTEPS 160
#define NSAMP (NRAYS*NSTEPS)
#define GG 160
#define GG2 (GG*GG)
#define GG3 (GG*GG2)
#define GM 80
#define GM2 (GM*GM)

#define NEARV 0.05f
#define DISTV 0.00625f
#define SVAL 80.0f
#define ACT_SHIFT_C (-9.2102403669758813f)
#define INV2H 40.0f          // 1/(2*VOXEL_SIZE)
#define MASK_THRES_C 1e-3f
#define FAST_THRES_C 1e-7f

// normalized 5-tap gaussian, sigma=1
#define KW0 0.05448868454964295f
#define KW1 0.24420134200323332f
#define KW2 0.40261994689424750f

__device__ __forceinline__ float sigmf(float x){ return 1.0f/(1.0f+__expf(-x)); }
__device__ __forceinline__ float softplusf_(float x){ return (x>20.0f)? x : log1pf(__expf(x)); }

__device__ __forceinline__ void tricoord(float p, int Gx, int& i0, float& fr){
  float u = (p + 1.0f)*0.5f*(float)(Gx-1);
  u = fminf(fmaxf(u, 0.0f), (float)(Gx-1));
  int i = (int)floorf(u);
  i = min(max(i,0), Gx-2);
  i0 = i; fr = u - (float)i;
}

// ---------------- fused y+z gaussian passes (zero-pad SAME), LDS tiled ----------------
// block 0 additionally zero-inits out rgb and cnt (stream-ordered before consumers).
__global__ __launch_bounds__(256) void ksmooth_yz(const float* __restrict__ in, float* __restrict__ out,
                                                  float* __restrict__ outbuf, int* __restrict__ cnt){
  __shared__ float S[36][37];
  __shared__ float Tz[36][33];
  const int bx = blockIdx.x;          // 160 * 25
  const int t = threadIdx.x;
  if (bx == 0){
    for (int i = t; i < NRAYS*3; i += 256) outbuf[i] = 0.0f;
    if (t == 0) *cnt = 0;
  }
  const int x  = bx / 25;
  const int tile = bx % 25;
  const int Y0 = (tile/5)*32, Z0 = (tile%5)*32;
  const float kw[5] = {KW0,KW1,KW2,KW1,KW0};
  for (int i = t; i < 36*36; i += 256){
    int r = i/36, c = i - (i/36)*36;
    int y = Y0 + r - 2, z = Z0 + c - 2;
    float v = 0.0f;
    if (y>=0 && y<GG && z>=0 && z<GG) v = in[(x*GG+y)*GG+z];
    S[r][c] = v;
  }
  __syncthreads();
  for (int i = t; i < 36*32; i += 256){
    int r = i >> 5, c = i & 31;
    float acc = 0.f;
    #pragma unroll
    for (int d=0; d<5; d++) acc += kw[d]*S[r][c+d];
    Tz[r][c] = acc;
  }
  __syncthreads();
  for (int i = t; i < 32*32; i += 256){
    int yy = i >> 5, c = i & 31;
    float acc = 0.f;
    #pragma unroll
    for (int d=0; d<5; d++) acc += kw[d]*Tz[yy+d][c];
    out[(x*GG + Y0+yy)*GG + Z0 + c] = acc;
  }
}

// ---------------- x-axis gaussian pass: sliding register window ----------------
#define XCH 32
__global__ __launch_bounds__(256) void ksmooth_x(const float* __restrict__ in, float* __restrict__ out){
  const int bid = blockIdx.x;             // (GG2/256) * (GG/XCH) = 100*5 = 500
  const int xc  = bid / (GG2/256);
  const int o   = (bid % (GG2/256))*256 + threadIdx.x;   // y*GG+z, coalesced
  const int x0  = xc*XCH;
  float w0 = (x0 >= 2) ? in[(x0-2)*GG2 + o] : 0.0f;
  float w1 = (x0 >= 1) ? in[(x0-1)*GG2 + o] : 0.0f;
  float w2 = in[x0*GG2 + o];
  float w3 = in[(x0+1)*GG2 + o];
  #pragma unroll 8
  for (int i = 0; i < XCH; i++){
    int xx = x0 + i;
    float w4 = (xx+2 < GG) ? in[(xx+2)*GG2 + o] : 0.0f;
    out[xx*GG2 + o] = KW0*w0 + KW1*w1 + KW2*w2 + KW1*w3 + KW0*w4;
    w0=w1; w1=w2; w2=w3; w3=w4;
  }
}

// ---------------- serial per-ray march: geometry + double scan + compaction ----------------
// Early break exact: once T1 <= 1e-7, all later w1 = alpha*T1 <= 1e-7 fail strict > test.
__global__ __launch_bounds__(64) void kmarch(
  const float* __restrict__ ro, const float* __restrict__ rd,
  const float* __restrict__ vd, const float* __restrict__ maskg,
  const float* __restrict__ sdfs,
  int* __restrict__ slist, float* __restrict__ sw, float* __restrict__ sgrad,
  int* __restrict__ cnt, float* __restrict__ out)
{
  int n = blockIdx.x*64 + threadIdx.x;
  if (n >= NRAYS) return;
  const float ox=ro[n*3+0], oy=ro[n*3+1], oz=ro[n*3+2];
  const float dx=rd[n*3+0], dy=rd[n*3+1], dz=rd[n*3+2];
  const float vx=vd[n*3+0], vy=vd[n*3+1], vz=vd[n*3+2];
  float T1=1.0f, T2=1.0f, cum=0.0f;
  for (int s=0; s<NSTEPS; s++){
    float tt = NEARV + DISTV*(float)s;
    float px = ox + dx*tt, py = oy + dy*tt, pz = oz + dz*tt;

    int mx,my,mz; float mfx,mfy,mfz;
    tricoord(px, GM, mx, mfx); tricoord(py, GM, my, mfy); tricoord(pz, GM, mz, mfz);
    int mid = (mx*GM + my)*GM + mz;
    float d000=maskg[mid],        d001=maskg[mid+1];
    float d010=maskg[mid+GM],     d011=maskg[mid+GM+1];
    float d100=maskg[mid+GM2],    d101=maskg[mid+GM2+1];
    float d110=maskg[mid+GM2+GM], d111=maskg[mid+GM2+GM+1];
    float m00 = d000 + (d001-d000)*mfz;
    float m01 = d010 + (d011-d010)*mfz;
    float m10 = d100 + (d101-d100)*mfz;
    float m11 = d110 + (d111-d110)*mfz;
    float m0 = m00 + (m01-m00)*mfy;
    float m1 = m10 + (m11-m10)*mfy;
    float dens = m0 + (m1-m0)*mfx;
    float malpha = 1.0f - __expf(-softplusf_(dens + ACT_SHIFT_C)*DISTV);

    int ix,iy,iz; float fx,fy,fz;
    tricoord(px, GG, ix, fx); tricoord(py, GG, iy, fy); tricoord(pz, GG, iz, fz);
    float sdf=0.0f, gx=0.0f, gy=0.0f, gz=0.0f;
    #pragma unroll
    for (int ca=0; ca<2; ca++){
      #pragma unroll
      for (int cb=0; cb<2; cb++){
        #pragma unroll
        for (int cc=0; cc<2; cc++){
          int a=ix+ca, b=iy+cb, c=iz+cc;
          float w = (ca?fx:1.0f-fx)*(cb?fy:1.0f-fy)*(cc?fz:1.0f-fz);
          int id = (a*GG + b)*GG + c;
          sdf += w*sdfs[id];
          if (a>=1 && a<=GG-2) gx += w*INV2H*(sdfs[id+GG2]-sdfs[id-GG2]);
          if (b>=1 && b<=GG-2) gy += w*INV2H*(sdfs[id+GG]-sdfs[id-GG]);
          if (c>=1 && c<=GG-2) gz += w*INV2H*(sdfs[id+1]-sdfs[id-1]);
        }
      }
    }
    float tc = vx*gx + vy*gy + vz*gz;
    float icos = fminf(tc, 0.0f);
    float e = icos*DISTV*0.5f;
    float prev = sigmf((sdf - e)*SVAL);
    float nxt  = sigmf((sdf + e)*SVAL);
    float alpha = (prev - nxt + 1e-5f)/(prev + 1e-5f);
    alpha = fminf(fmaxf(alpha, 0.0f), 1.0f);
    if (!(malpha >= MASK_THRES_C)) alpha = 0.0f;

    float w1 = alpha*T1; T1 *= (1.0f - alpha);
    float a2 = (w1 > FAST_THRES_C) ? alpha : 0.0f;
    float wv = a2*T2;   T2 *= (1.0f - a2);
    cum += wv;
    if (wv > 0.0f){
      int pos = atomicAdd(cnt, 1);
      slist[pos] = n*NSTEPS + s;
      sw[pos] = wv;
      sgrad[pos*3+0]=gx; sgrad[pos*3+1]=gy; sgrad[pos*3+2]=gz;
    }
    if (T1 <= FAST_THRES_C) break;
  }
  out[NRAYS*3 + n] = T2;
  out[NRAYS*4 + n] = 1.0f - cum;
}

// ---------------- compacted MLP: one head per block, 8 samples, 32 thr/sample ----------------
__global__ __launch_bounds__(256) void kmlp3(
  const float* __restrict__ ro, const float* __restrict__ rd,
  const float* __restrict__ vd, const int* __restrict__ em,
  const float* __restrict__ offc, const float* __restrict__ emoc,
  const int* __restrict__ slist, const float* __restrict__ sw,
  const float* __restrict__ sgrad, const int* __restrict__ cnt,
  const float* __restrict__ W0o, const float* __restrict__ b0o,
  const float* __restrict__ W1o, const float* __restrict__ b1o,
  const float* __restrict__ W2o, const float* __restrict__ b2o,
  const float* __restrict__ W0e, const float* __restrict__ b0e,
  const float* __restrict__ W1e, const float* __restrict__ b1e,
  const float* __restrict__ W2e, const float* __restrict__ b2e,
  float* __restrict__ out)
{
  __shared__ float X[8][80];
  __shared__ float H[8][132];
  __shared__ float H2[8][132];
  __shared__ float OUTB[8][3];
  __shared__ float WSH[8];
  __shared__ float GS[8][3];
  __shared__ int SSAMP[8];
  __shared__ int SEM[8];
  __shared__ int s_go;

  const int t = threadIdx.x;
  const int count = *cnt;
  const int head = blockIdx.x & 1;
  const int cstride = gridDim.x >> 1;

  const float* W0 = head ? W0e : W0o;  const float* b0 = head ? b0e : b0o;
  const float* W1 = head ? W1e : W1o;  const float* b1 = head ? b1e : b1o;
  const float* W2 = head ? W2e : W2o;  const float* b2 = head ? b2e : b2o;
  const float* cg = head ? emoc : offc;
  const float4* W04 = (const float4*)W0;
  const float4* W14 = (const float4*)W1;

  const int sp   = t >> 5;     // sample 0..7
  const int lane = t & 31;     // 32 threads per sample, 4 outputs each

  for (int chunk = blockIdx.x >> 1; chunk*8 < count; chunk += cstride) {
    const int base = chunk*8;
    if (t == 0) s_go = 0;
    if (t < 8) {
      int i = base + t;
      bool vld = (i < count);
      int samp = vld ? slist[i] : 0;
      SSAMP[t] = samp;
      WSH[t]   = vld ? sw[i] : 0.0f;
      GS[t][0] = vld ? sgrad[i*3+0] : 0.0f;
      GS[t][1] = vld ? sgrad[i*3+1] : 0.0f;
      GS[t][2] = vld ? sgrad[i*3+2] : 0.0f;
      SEM[t]   = vld ? em[samp/NSTEPS] : 0;
    }
    __syncthreads();
    if (t < 8) {
      bool live = (WSH[t] > 0.0f) && (head == 0 || SEM[t] != 0);
      if (live) s_go = 1;
    }
    __syncthreads();

    if (s_go) {
      // ---- features: s = t&7 sample, r = t>>3 group (0..31, 10 used) ----
      {
        const int s = t & 7;
        const int r = t >> 3;
        const int samp = SSAMP[s];
        const int n = samp / NSTEPS;
        const int step = samp - n*NSTEPS;
        const float tt = NEARV + DISTV*(float)step;
        const float px = ro[n*3+0] + rd[n*3+0]*tt;
        const float py = ro[n*3+1] + rd[n*3+1]*tt;
        const float pz = ro[n*3+2] + rd[n*3+2]*tt;
        if (r < 3) {
          int ix,iy,iz; float fx,fy,fz;
          tricoord(px, GG, ix, fx); tricoord(py, GG, iy, fy); tricoord(pz, GG, iz, fz);
          const float* g = cg + (size_t)r * GG3;
          const int id = (ix*GG + iy)*GG + iz;
          float v000=g[id],        v001=g[id+1];
          float v010=g[id+GG],     v011=g[id+GG+1];
          float v100=g[id+GG2],    v101=g[id+GG2+1];
          float v110=g[id+GG2+GG], v111=g[id+GG2+GG+1];
          float c00 = v000 + (v001-v000)*fz;
          float c01 = v010 + (v011-v010)*fz;
          float c10 = v100 + (v101-v100)*fz;
          float c11 = v110 + (v111-v110)*fz;
          float c0 = c00 + (c01-c00)*fy;
          float c1 = c10 + (c11-c10)*fy;
          X[s][r] = c0 + (c1-c0)*fx;
        } else if (r == 3) {
          X[s][3] = (px+1.0f)*0.5f;
          X[s][4] = (py+1.0f)*0.5f;
          X[s][5] = (pz+1.0f)*0.5f;
          float gx = GS[s][0], gy = GS[s][1], gz = GS[s][2];
          float inv = 1.0f/(sqrtf(gx*gx+gy*gy+gz*gz)+1e-5f);
          X[s][72] = gx*inv; X[s][73] = gy*inv; X[s][74] = gz*inv;
        } else if (r < 7) {
          const int a = r - 4;
          const float coord = (a==0)?px:((a==1)?py:pz);
          const float rxyz = (coord+1.0f)*0.5f;
          float fr = 1.0f;
          #pragma unroll
          for (int q = 0; q < 5; q++) {
            float e = rxyz*fr; fr *= 2.0f;
            X[s][6  + a*5 + q] = __sinf(e);
            X[s][21 + a*5 + q] = __cosf(e);
          }
        } else if (r < 10) {
          const int a = r - 7;
          const float v = vd[n*3+a];
          float fr = 1.0f;
          #pragma unroll
          for (int q = 0; q < 4; q++) {
            float e = v*fr; fr *= 2.0f;
            X[s][36 + a*4 + q] = e;
            X[s][48 + a*4 + q] = __sinf(e);
            X[s][60 + a*4 + q] = __cosf(e);
          }
        }
      }
      __syncthreads();

      // ---- layer 0: 75 -> 128 ----
      {
        float4 acc = ((const float4*)b0)[lane];
        #pragma unroll 5
        for (int k=0; k<75; k++){
          float x = X[sp][k];
          float4 w = W04[k*32 + lane];
          acc.x += x*w.x; acc.y += x*w.y; acc.z += x*w.z; acc.w += x*w.w;
        }
        H[sp][lane*4+0] = fmaxf(acc.x,0.0f);
        H[sp][lane*4+1] = fmaxf(acc.y,0.0f);
        H[sp][lane*4+2] = fmaxf(acc.z,0.0f);
        H[sp][lane*4+3] = fmaxf(acc.w,0.0f);
      }
      __syncthreads();

      // ---- layer 1: 128 -> 128 ----
      {
        float4 acc = ((const float4*)b1)[lane];
        #pragma unroll 8
        for (int k=0; k<128; k++){
          float x = H[sp][k];
          float4 w = W14[k*32 + lane];
          acc.x += x*w.x; acc.y += x*w.y; acc.z += x*w.z; acc.w += x*w.w;
        }
        H2[sp][lane*4+0] = fmaxf(acc.x,0.0f);
        H2[sp][lane*4+1] = fmaxf(acc.y,0.0f);
        H2[sp][lane*4+2] = fmaxf(acc.z,0.0f);
        H2[sp][lane*4+3] = fmaxf(acc.w,0.0f);
      }
      __syncthreads();

      // ---- layer 2: 128 -> 3, 32-lane shuffle reduce ----
      {
        float a0=0.0f, a1=0.0f, a2v=0.0f;
        #pragma unroll
        for (int i=0;i<4;i++){
          int k = lane*4+i;
          float h = H2[sp][k];
          a0  += h*W2[k*3+0];
          a1  += h*W2[k*3+1];
          a2v += h*W2[k*3+2];
        }
        #pragma unroll
        for (int d=16; d>=1; d>>=1){
          a0  += __shfl_down(a0,  d, 32);
          a1  += __shfl_down(a1,  d, 32);
          a2v += __shfl_down(a2v, d, 32);
        }
        if (lane == 0){
          OUTB[sp][0] = sigmf(a0  + b2[0]);
          OUTB[sp][1] = sigmf(a1  + b2[1]);
          OUTB[sp][2] = sigmf(a2v + b2[2]);
        }
      }
      __syncthreads();

      if (t < 24) {
        int s2 = t/3, c = t - s2*3;
        float w = WSH[s2];
        if (w > 0.0f && (head == 0 || SEM[s2] != 0)) {
          int n2 = SSAMP[s2]/NSTEPS;
          atomicAdd(&out[n2*3 + c], w * OUTB[s2][c]);
        }
      }
    }
    __syncthreads();
  }
}

extern "C" void kernel_launch(void* const* d_in, const int* in_sizes, int n_in,
                              void* d_out, int out_size, void* d_ws, size_t ws_size,
                              hipStream_t stream) {
  const float* ro    = (const float*)d_in[0];
  const float* rd    = (const float*)d_in[1];
  const float* vd    = (const float*)d_in[2];
  const int*   em    = (const int*)d_in[3];
  const float* sdfg  = (const float*)d_in[4];
  const float* maskg = (const float*)d_in[5];
  const float* offc  = (const float*)d_in[6];
  const float* emoc  = (const float*)d_in[7];
  const float* W0o = (const float*)d_in[8];
  const float* b0o = (const float*)d_in[9];
  const float* W1o = (const float*)d_in[10];
  const float* b1o = (const float*)d_in[11];
  const float* W2o = (const float*)d_in[12];
  const float* b2o = (const float*)d_in[13];
  const float* W0e = (const float*)d_in[14];
  const float* b0e = (const float*)d_in[15];
  const float* W1e = (const float*)d_in[16];
  const float* b1e = (const float*)d_in[17];
  const float* W2e = (const float*)d_in[18];
  const float* b2e = (const float*)d_in[19];

  float* out = (float*)d_out;
  float* ws  = (float*)d_ws;
  float* bufA  = ws;                         // GG3
  float* bufB  = ws + GG3;                   // GG3
  float* swb   = ws + 2*GG3;                 // NSAMP
  float* sgradb= swb + NSAMP;                // 3*NSAMP
  int*   slist = (int*)(sgradb + 3*(size_t)NSAMP);  // NSAMP
  int*   cnt   = slist + NSAMP;              // 1

  ksmooth_yz<<<GG*25, 256, 0, stream>>>(sdfg, bufB, out, cnt);
  ksmooth_x<<<(GG2/256)*(GG/XCH), 256, 0, stream>>>(bufB, bufA);

  kmarch<<<NRAYS/64, 64, 0, stream>>>(ro, rd, vd, maskg, bufA,
                                      slist, swb, sgradb, cnt, out);

  kmlp3<<<2048, 256, 0, stream>>>(ro, rd, vd, em, offc, emoc,
                                  slist, swb, sgradb, cnt,
                                  W0o,b0o,W1o,b1o,W2o,b2o,
                                  W0e,b0e,W1e,b1e,W2e,b2e, out);
}

// Round 6
// 66.888 us; speedup vs baseline: 1.9140x; 1.1342x over previous
//
#include <hip/hip_runtime.h>

#define NRAYS 4096
#define NSTEPS 160
#define NSAMP (NRAYS*NSTEPS)
#define GG 160
#define GG2 (GG*GG)
#define GG3 (GG*GG2)
#define GM 80
#define GM2 (GM*GM)

#define NEARV 0.05f
#define DISTV 0.00625f
#define SVAL 80.0f
#define ACT_SHIFT_C (-9.2102403669758813f)
#define INV2H 40.0f          // 1/(2*VOXEL_SIZE)
#define MASK_THRES_C 1e-3f
#define FAST_THRES_C 1e-7f

// normalized 5-tap gaussian, sigma=1
#define KW0 0.05448868454964295f
#define KW1 0.24420134200323332f
#define KW2 0.40261994689424750f

__device__ __forceinline__ float sigmf(float x){ return 1.0f/(1.0f+__expf(-x)); }
__device__ __forceinline__ float softplusf_(float x){ return (x>20.0f)? x : log1pf(__expf(x)); }

__device__ __forceinline__ void tricoord(float p, int Gx, int& i0, float& fr){
  float u = (p + 1.0f)*0.5f*(float)(Gx-1);
  u = fminf(fmaxf(u, 0.0f), (float)(Gx-1));
  int i = (int)floorf(u);
  i = min(max(i,0), Gx-2);
  i0 = i; fr = u - (float)i;
}

// ---------------- fused y+z gaussian passes (zero-pad SAME), LDS tiled ----------------
// block 0 additionally zero-inits out rgb and cnt (stream-ordered before consumers).
__global__ __launch_bounds__(256) void ksmooth_yz(const float* __restrict__ in, float* __restrict__ out,
                                                  float* __restrict__ outbuf, int* __restrict__ cnt){
  __shared__ float S[36][37];
  __shared__ float Tz[36][33];
  const int bx = blockIdx.x;          // 160 * 25
  const int t = threadIdx.x;
  if (bx == 0){
    for (int i = t; i < NRAYS*3; i += 256) outbuf[i] = 0.0f;
    if (t == 0) *cnt = 0;
  }
  const int x  = bx / 25;
  const int tile = bx % 25;
  const int Y0 = (tile/5)*32, Z0 = (tile%5)*32;
  const float kw[5] = {KW0,KW1,KW2,KW1,KW0};
  for (int i = t; i < 36*36; i += 256){
    int r = i/36, c = i - (i/36)*36;
    int y = Y0 + r - 2, z = Z0 + c - 2;
    float v = 0.0f;
    if (y>=0 && y<GG && z>=0 && z<GG) v = in[(x*GG+y)*GG+z];
    S[r][c] = v;
  }
  __syncthreads();
  for (int i = t; i < 36*32; i += 256){
    int r = i >> 5, c = i & 31;
    float acc = 0.f;
    #pragma unroll
    for (int d=0; d<5; d++) acc += kw[d]*S[r][c+d];
    Tz[r][c] = acc;
  }
  __syncthreads();
  for (int i = t; i < 32*32; i += 256){
    int yy = i >> 5, c = i & 31;
    float acc = 0.f;
    #pragma unroll
    for (int d=0; d<5; d++) acc += kw[d]*Tz[yy+d][c];
    out[(x*GG + Y0+yy)*GG + Z0 + c] = acc;
  }
}

// ---------------- serial per-ray march on yz-smoothed grid, x-conv on the fly ----------------
// Y = yz-smoothed grid. Smoothed s(a,b,c) = sum_d kw[d]*Y(a+d,b,c) (zero-pad in x).
// Gradients are central differences of the fully-smoothed grid, zero at each axis boundary.
// Early break exact: once T1 <= 1e-7, all later w1 = alpha*T1 <= 1e-7 fail strict > test.
__global__ __launch_bounds__(64) void kmarch(
  const float* __restrict__ ro, const float* __restrict__ rd,
  const float* __restrict__ vd, const float* __restrict__ maskg,
  const float* __restrict__ Y,
  int* __restrict__ slist, float* __restrict__ sw, float* __restrict__ sgrad,
  int* __restrict__ cnt, float* __restrict__ out)
{
  int n = blockIdx.x*64 + threadIdx.x;
  if (n >= NRAYS) return;
  const float ox=ro[n*3+0], oy=ro[n*3+1], oz=ro[n*3+2];
  const float dx=rd[n*3+0], dy=rd[n*3+1], dz=rd[n*3+2];
  const float vx=vd[n*3+0], vy=vd[n*3+1], vz=vd[n*3+2];
  const float kwc[5] = {KW0,KW1,KW2,KW1,KW0};
  float T1=1.0f, T2=1.0f, cum=0.0f;
  for (int s=0; s<NSTEPS; s++){
    float tt = NEARV + DISTV*(float)s;
    float px = ox + dx*tt, py = oy + dy*tt, pz = oz + dz*tt;

    // mask-cache trilerp on 80^3 grid
    int mx,my,mz; float mfx,mfy,mfz;
    tricoord(px, GM, mx, mfx); tricoord(py, GM, my, mfy); tricoord(pz, GM, mz, mfz);
    int mid = (mx*GM + my)*GM + mz;
    float d000=maskg[mid],        d001=maskg[mid+1];
    float d010=maskg[mid+GM],     d011=maskg[mid+GM+1];
    float d100=maskg[mid+GM2],    d101=maskg[mid+GM2+1];
    float d110=maskg[mid+GM2+GM], d111=maskg[mid+GM2+GM+1];
    float m00 = d000 + (d001-d000)*mfz;
    float m01 = d010 + (d011-d010)*mfz;
    float m10 = d100 + (d101-d100)*mfz;
    float m11 = d110 + (d111-d110)*mfz;
    float m0 = m00 + (m01-m00)*mfy;
    float m1 = m10 + (m11-m10)*mfy;
    float dens = m0 + (m1-m0)*mfx;
    float malpha = 1.0f - __expf(-softplusf_(dens + ACT_SHIFT_C)*DISTV);

    // sdf + gradient trilerp with on-the-fly x-conv over Y
    int ix,iy,iz; float fx,fy,fz;
    tricoord(px, GG, ix, fx); tricoord(py, GG, iy, fy); tricoord(pz, GG, iz, fz);

    // R rows: Y(ix-3+j, iy+jb, iz+jc), j=0..7
    float R[2][2][8];
    #pragma unroll
    for (int jb=0;jb<2;jb++)
      #pragma unroll
      for (int jc=0;jc<2;jc++)
        #pragma unroll
        for (int j=0;j<8;j++){
          int a = ix-3+j;
          R[jb][jc][j] = (a>=0 && a<GG) ? Y[(a*GG + iy+jb)*GG + iz+jc] : 0.0f;
        }
    // extra rows for gy/gz: base x = ix-2, 6 taps
    const bool hasym = (iy>=1), hasyp = (iy<=GG-3);
    const bool haszm = (iz>=1), haszp = (iz<=GG-3);
    float Eym[2][6], Eyp[2][6], Ezm[2][6], Ezp[2][6];
    #pragma unroll
    for (int jc=0;jc<2;jc++)
      #pragma unroll
      for (int j=0;j<6;j++){
        int a = ix-2+j;
        bool ax = (a>=0 && a<GG);
        Eym[jc][j] = (hasym && ax) ? Y[(a*GG + iy-1)*GG + iz+jc] : 0.0f;
        Eyp[jc][j] = (hasyp && ax) ? Y[(a*GG + iy+2)*GG + iz+jc] : 0.0f;
      }
    #pragma unroll
    for (int jb=0;jb<2;jb++)
      #pragma unroll
      for (int j=0;j<6;j++){
        int a = ix-2+j;
        bool ax = (a>=0 && a<GG);
        Ezm[jb][j] = (haszm && ax) ? Y[(a*GG + iy+jb)*GG + iz-1] : 0.0f;
        Ezp[jb][j] = (haszp && ax) ? Y[(a*GG + iy+jb)*GG + iz+2] : 0.0f;
      }

    float sdf=0.0f, gx=0.0f, gy=0.0f, gz=0.0f;
    #pragma unroll
    for (int ja=0;ja<2;ja++){
      #pragma unroll
      for (int jb=0;jb<2;jb++){
        #pragma unroll
        for (int jc=0;jc<2;jc++){
          float w = (ja?fx:1.0f-fx)*(jb?fy:1.0f-fy)*(jc?fz:1.0f-fz);
          const float* r = R[jb][jc];
          float s0=0.0f;
          #pragma unroll
          for (int t2=0;t2<5;t2++) s0 += kwc[t2]*r[ja+1+t2];
          sdf += w*s0;
          int a = ix+ja, b = iy+jb, c = iz+jc;
          if (a>=1 && a<=GG-2){
            float sp=0.0f, sm=0.0f;
            #pragma unroll
            for (int t2=0;t2<5;t2++){ sp += kwc[t2]*r[ja+2+t2]; sm += kwc[t2]*r[ja+t2]; }
            gx += w*INV2H*(sp-sm);
          }
          if (b>=1 && b<=GG-2){
            float acc=0.0f;
            if (jb==0){
              const float* up = R[1][jc];   // b+1 = iy+1, base ix-3
              const float* dn = Eym[jc];    // b-1 = iy-1, base ix-2
              #pragma unroll
              for (int t2=0;t2<5;t2++) acc += kwc[t2]*(up[ja+1+t2] - dn[ja+t2]);
            } else {
              const float* up = Eyp[jc];    // b+1 = iy+2, base ix-2
              const float* dn = R[0][jc];   // b-1 = iy,   base ix-3
              #pragma unroll
              for (int t2=0;t2<5;t2++) acc += kwc[t2]*(up[ja+t2] - dn[ja+1+t2]);
            }
            gy += w*INV2H*acc;
          }
          if (c>=1 && c<=GG-2){
            float acc=0.0f;
            if (jc==0){
              const float* up = R[jb][1];   // c+1 = iz+1, base ix-3
              const float* dn = Ezm[jb];    // c-1 = iz-1, base ix-2
              #pragma unroll
              for (int t2=0;t2<5;t2++) acc += kwc[t2]*(up[ja+1+t2] - dn[ja+t2]);
            } else {
              const float* up = Ezp[jb];    // c+1 = iz+2, base ix-2
              const float* dn = R[jb][0];   // c-1 = iz,   base ix-3
              #pragma unroll
              for (int t2=0;t2<5;t2++) acc += kwc[t2]*(up[ja+t2] - dn[ja+1+t2]);
            }
            gz += w*INV2H*acc;
          }
        }
      }
    }

    float tc = vx*gx + vy*gy + vz*gz;
    float icos = fminf(tc, 0.0f);
    float e = icos*DISTV*0.5f;
    float prev = sigmf((sdf - e)*SVAL);
    float nxt  = sigmf((sdf + e)*SVAL);
    float alpha = (prev - nxt + 1e-5f)/(prev + 1e-5f);
    alpha = fminf(fmaxf(alpha, 0.0f), 1.0f);
    if (!(malpha >= MASK_THRES_C)) alpha = 0.0f;

    float w1 = alpha*T1; T1 *= (1.0f - alpha);
    float a2 = (w1 > FAST_THRES_C) ? alpha : 0.0f;
    float wv = a2*T2;   T2 *= (1.0f - a2);
    cum += wv;
    if (wv > 0.0f){
      int pos = atomicAdd(cnt, 1);
      slist[pos] = n*NSTEPS + s;
      sw[pos] = wv;
      sgrad[pos*3+0]=gx; sgrad[pos*3+1]=gy; sgrad[pos*3+2]=gz;
    }
    if (T1 <= FAST_THRES_C) break;
  }
  out[NRAYS*3 + n] = T2;
  out[NRAYS*4 + n] = 1.0f - cum;
}

// ---------------- compacted MLP: one head per block, 8 samples, 32 thr/sample ----------------
__global__ __launch_bounds__(256) void kmlp3(
  const float* __restrict__ ro, const float* __restrict__ rd,
  const float* __restrict__ vd, const int* __restrict__ em,
  const float* __restrict__ offc, const float* __restrict__ emoc,
  const int* __restrict__ slist, const float* __restrict__ sw,
  const float* __restrict__ sgrad, const int* __restrict__ cnt,
  const float* __restrict__ W0o, const float* __restrict__ b0o,
  const float* __restrict__ W1o, const float* __restrict__ b1o,
  const float* __restrict__ W2o, const float* __restrict__ b2o,
  const float* __restrict__ W0e, const float* __restrict__ b0e,
  const float* __restrict__ W1e, const float* __restrict__ b1e,
  const float* __restrict__ W2e, const float* __restrict__ b2e,
  float* __restrict__ out)
{
  __shared__ float X[8][80];
  __shared__ float H[8][132];
  __shared__ float H2[8][132];
  __shared__ float OUTB[8][3];
  __shared__ float WSH[8];
  __shared__ float GS[8][3];
  __shared__ int SSAMP[8];
  __shared__ int SEM[8];
  __shared__ int s_go;

  const int t = threadIdx.x;
  const int count = *cnt;
  const int head = blockIdx.x & 1;
  const int cstride = gridDim.x >> 1;

  const float* W0 = head ? W0e : W0o;  const float* b0 = head ? b0e : b0o;
  const float* W1 = head ? W1e : W1o;  const float* b1 = head ? b1e : b1o;
  const float* W2 = head ? W2e : W2o;  const float* b2 = head ? b2e : b2o;
  const float* cg = head ? emoc : offc;
  const float4* W04 = (const float4*)W0;
  const float4* W14 = (const float4*)W1;

  const int sp   = t >> 5;     // sample 0..7
  const int lane = t & 31;     // 32 threads per sample, 4 outputs each

  for (int chunk = blockIdx.x >> 1; chunk*8 < count; chunk += cstride) {
    const int base = chunk*8;
    if (t == 0) s_go = 0;
    if (t < 8) {
      int i = base + t;
      bool vld = (i < count);
      int samp = vld ? slist[i] : 0;
      SSAMP[t] = samp;
      WSH[t]   = vld ? sw[i] : 0.0f;
      GS[t][0] = vld ? sgrad[i*3+0] : 0.0f;
      GS[t][1] = vld ? sgrad[i*3+1] : 0.0f;
      GS[t][2] = vld ? sgrad[i*3+2] : 0.0f;
      SEM[t]   = vld ? em[samp/NSTEPS] : 0;
    }
    __syncthreads();
    if (t < 8) {
      bool live = (WSH[t] > 0.0f) && (head == 0 || SEM[t] != 0);
      if (live) s_go = 1;
    }
    __syncthreads();

    if (s_go) {
      // ---- features: s = t&7 sample, r = t>>3 group (0..31, 10 used) ----
      {
        const int s = t & 7;
        const int r = t >> 3;
        const int samp = SSAMP[s];
        const int n = samp / NSTEPS;
        const int step = samp - n*NSTEPS;
        const float tt = NEARV + DISTV*(float)step;
        const float px = ro[n*3+0] + rd[n*3+0]*tt;
        const float py = ro[n*3+1] + rd[n*3+1]*tt;
        const float pz = ro[n*3+2] + rd[n*3+2]*tt;
        if (r < 3) {
          int ix,iy,iz; float fx,fy,fz;
          tricoord(px, GG, ix, fx); tricoord(py, GG, iy, fy); tricoord(pz, GG, iz, fz);
          const float* g = cg + (size_t)r * GG3;
          const int id = (ix*GG + iy)*GG + iz;
          float v000=g[id],        v001=g[id+1];
          float v010=g[id+GG],     v011=g[id+GG+1];
          float v100=g[id+GG2],    v101=g[id+GG2+1];
          float v110=g[id+GG2+GG], v111=g[id+GG2+GG+1];
          float c00 = v000 + (v001-v000)*fz;
          float c01 = v010 + (v011-v010)*fz;
          float c10 = v100 + (v101-v100)*fz;
          float c11 = v110 + (v111-v110)*fz;
          float c0 = c00 + (c01-c00)*fy;
          float c1 = c10 + (c11-c10)*fy;
          X[s][r] = c0 + (c1-c0)*fx;
        } else if (r == 3) {
          X[s][3] = (px+1.0f)*0.5f;
          X[s][4] = (py+1.0f)*0.5f;
          X[s][5] = (pz+1.0f)*0.5f;
          float gx = GS[s][0], gy = GS[s][1], gz = GS[s][2];
          float inv = 1.0f/(sqrtf(gx*gx+gy*gy+gz*gz)+1e-5f);
          X[s][72] = gx*inv; X[s][73] = gy*inv; X[s][74] = gz*inv;
        } else if (r < 7) {
          const int a = r - 4;
          const float coord = (a==0)?px:((a==1)?py:pz);
          const float rxyz = (coord+1.0f)*0.5f;
          float fr = 1.0f;
          #pragma unroll
          for (int q = 0; q < 5; q++) {
            float e = rxyz*fr; fr *= 2.0f;
            X[s][6  + a*5 + q] = __sinf(e);
            X[s][21 + a*5 + q] = __cosf(e);
          }
        } else if (r < 10) {
          const int a = r - 7;
          const float v = vd[n*3+a];
          float fr = 1.0f;
          #pragma unroll
          for (int q = 0; q < 4; q++) {
            float e = v*fr; fr *= 2.0f;
            X[s][36 + a*4 + q] = e;
            X[s][48 + a*4 + q] = __sinf(e);
            X[s][60 + a*4 + q] = __cosf(e);
          }
        }
      }
      __syncthreads();

      // ---- layer 0: 75 -> 128 ----
      {
        float4 acc = ((const float4*)b0)[lane];
        #pragma unroll 5
        for (int k=0; k<75; k++){
          float x = X[sp][k];
          float4 w = W04[k*32 + lane];
          acc.x += x*w.x; acc.y += x*w.y; acc.z += x*w.z; acc.w += x*w.w;
        }
        H[sp][lane*4+0] = fmaxf(acc.x,0.0f);
        H[sp][lane*4+1] = fmaxf(acc.y,0.0f);
        H[sp][lane*4+2] = fmaxf(acc.z,0.0f);
        H[sp][lane*4+3] = fmaxf(acc.w,0.0f);
      }
      __syncthreads();

      // ---- layer 1: 128 -> 128 ----
      {
        float4 acc = ((const float4*)b1)[lane];
        #pragma unroll 8
        for (int k=0; k<128; k++){
          float x = H[sp][k];
          float4 w = W14[k*32 + lane];
          acc.x += x*w.x; acc.y += x*w.y; acc.z += x*w.z; acc.w += x*w.w;
        }
        H2[sp][lane*4+0] = fmaxf(acc.x,0.0f);
        H2[sp][lane*4+1] = fmaxf(acc.y,0.0f);
        H2[sp][lane*4+2] = fmaxf(acc.z,0.0f);
        H2[sp][lane*4+3] = fmaxf(acc.w,0.0f);
      }
      __syncthreads();

      // ---- layer 2: 128 -> 3, 32-lane shuffle reduce ----
      {
        float a0=0.0f, a1=0.0f, a2v=0.0f;
        #pragma unroll
        for (int i=0;i<4;i++){
          int k = lane*4+i;
          float h = H2[sp][k];
          a0  += h*W2[k*3+0];
          a1  += h*W2[k*3+1];
          a2v += h*W2[k*3+2];
        }
        #pragma unroll
        for (int d=16; d>=1; d>>=1){
          a0  += __shfl_down(a0,  d, 32);
          a1  += __shfl_down(a1,  d, 32);
          a2v += __shfl_down(a2v, d, 32);
        }
        if (lane == 0){
          OUTB[sp][0] = sigmf(a0  + b2[0]);
          OUTB[sp][1] = sigmf(a1  + b2[1]);
          OUTB[sp][2] = sigmf(a2v + b2[2]);
        }
      }
      __syncthreads();

      if (t < 24) {
        int s2 = t/3, c = t - s2*3;
        float w = WSH[s2];
        if (w > 0.0f && (head == 0 || SEM[s2] != 0)) {
          int n2 = SSAMP[s2]/NSTEPS;
          atomicAdd(&out[n2*3 + c], w * OUTB[s2][c]);
        }
      }
    }
    __syncthreads();
  }
}

extern "C" void kernel_launch(void* const* d_in, const int* in_sizes, int n_in,
                              void* d_out, int out_size, void* d_ws, size_t ws_size,
                              hipStream_t stream) {
  const float* ro    = (const float*)d_in[0];
  const float* rd    = (const float*)d_in[1];
  const float* vd    = (const float*)d_in[2];
  const int*   em    = (const int*)d_in[3];
  const float* sdfg  = (const float*)d_in[4];
  const float* maskg = (const float*)d_in[5];
  const float* offc  = (const float*)d_in[6];
  const float* emoc  = (const float*)d_in[7];
  const float* W0o = (const float*)d_in[8];
  const float* b0o = (const float*)d_in[9];
  const float* W1o = (const float*)d_in[10];
  const float* b1o = (const float*)d_in[11];
  const float* W2o = (const float*)d_in[12];
  const float* b2o = (const float*)d_in[13];
  const float* W0e = (const float*)d_in[14];
  const float* b0e = (const float*)d_in[15];
  const float* W1e = (const float*)d_in[16];
  const float* b1e = (const float*)d_in[17];
  const float* W2e = (const float*)d_in[18];
  const float* b2e = (const float*)d_in[19];

  float* out = (float*)d_out;
  float* ws  = (float*)d_ws;
  float* bufB  = ws;                         // GG3 (yz-smoothed)
  float* swb   = ws + GG3;                   // NSAMP
  float* sgradb= swb + NSAMP;                // 3*NSAMP
  int*   slist = (int*)(sgradb + 3*(size_t)NSAMP);  // NSAMP
  int*   cnt   = slist + NSAMP;              // 1

  ksmooth_yz<<<GG*25, 256, 0, stream>>>(sdfg, bufB, out, cnt);

  kmarch<<<NRAYS/64, 64, 0, stream>>>(ro, rd, vd, maskg, bufB,
                                      slist, swb, sgradb, cnt, out);

  kmlp3<<<2048, 256, 0, stream>>>(ro, rd, vd, em, offc, emoc,
                                  slist, swb, sgradb, cnt,
                                  W0o,b0o,W1o,b1o,W2o,b2o,
                                  W0e,b0e,W1e,b1e,W2e,b2e, out);
}